// Round 7
// baseline (181.696 us; speedup 1.0000x reference)
//
#include <hip/hip_runtime.h>

// Problem constants: x [B,S,F], Wq/Wk/Wv [F,D], out [B,S,D]
constexpr int Bc = 4, Sc = 4096, Fc = 512, Dc = 64;
constexpr int SPLIT = 8;            // split-K over keys in attention
constexpr int KT = 64;              // keys per tile
constexpr int TILES = (Sc / SPLIT) / KT;  // 8

typedef __attribute__((ext_vector_type(8)))  short  short8;   // 8 bf16
typedef __attribute__((ext_vector_type(4)))  float  float4v;
typedef __attribute__((ext_vector_type(16))) float  float16v;
typedef __attribute__((ext_vector_type(2)))  unsigned int uint2v;

__device__ inline unsigned short f2bf(float f) {
    union { float f; unsigned u; } v; v.f = f;
    unsigned r = v.u + 0x7FFF + ((v.u >> 16) & 1);   // RTNE
    return (unsigned short)(r >> 16);
}
__device__ inline unsigned pk2(float a, float b) {   // pack 2 floats -> 2 bf16 (RTNE)
    union { float f; unsigned u; } x, y; x.f = a; y.f = b;
    unsigned ra = x.u + 0x7FFF + ((x.u >> 16) & 1);
    unsigned rb = y.u + 0x7FFF + ((y.u >> 16) & 1);
    return (ra >> 16) | (rb & 0xFFFF0000u);
}
// T12: single-instruction pack of 2 f32 -> 2 bf16 (RTNE, same as pk2).
__device__ inline unsigned cvtpk2(float lo, float hi) {
    unsigned r;
    asm("v_cvt_pk_bf16_f32 %0, %1, %2" : "=v"(r) : "v"(lo), "v"(hi));
    return r;
}
// native v_exp_f32 (2^x)
__device__ inline float exp2fast(float x) {
#if defined(__has_builtin) && __has_builtin(__builtin_amdgcn_exp2f)
    return __builtin_amdgcn_exp2f(x);
#else
    return __expf(x * 0.69314718055994531f);
#endif
}

// swap the 32-lane halves of two registers: a' = {a.lo | b.lo}, b' = {a.hi | b.hi}
__device__ inline void swap32(unsigned& a, unsigned& b) {
#if defined(__has_builtin) && __has_builtin(__builtin_amdgcn_permlane32_swap)
    uint2v r = __builtin_amdgcn_permlane32_swap(a, b, false, false);
    a = r[0]; b = r[1];
#else
    unsigned ax = (unsigned)__shfl_xor((int)a, 32);
    unsigned bx = (unsigned)__shfl_xor((int)b, 32);
    int upper = (threadIdx.x & 32) != 0;
    unsigned na = upper ? bx : a;
    unsigned nb = upper ? b  : ax;
    a = na; b = nb;
#endif
}

// ---------------------------------------------------------------------------
// Prep: Wf in MFMA-FRAGMENT ORDER (unchanged) + zero the split-K semaphores.
// ---------------------------------------------------------------------------
__global__ __launch_bounds__(256) void prep_kernel(
    const float* __restrict__ Wq, const float* __restrict__ Wk,
    const float* __restrict__ Wv, unsigned short* __restrict__ Wf,
    unsigned* __restrict__ sem)
{
    int wi = blockIdx.x * 256 + threadIdx.x;     // 12288 threads (48 blocks)
    if (wi < (Sc / 128) * Bc) sem[wi] = 0u;      // 128 semaphores
    int lane = wi & 63;
    int kc = (wi >> 6) & 15;
    int nt = wi >> 10;                           // 0..11
    int lm = lane & 15, quad = lane >> 4;
    int n = nt * 16 + lm;                        // 0..191
    const float* W = (n < 64) ? Wq : (n < 128) ? Wk : Wv;
    int nc = n & 63;
    float scale = (n < 64) ? 0.18033688011112042f : 1.0f;  // 0.125*log2(e)
    int kbase = kc * 32 + quad * 8;
    union { uint4 v; unsigned short s[8]; } tmp;
    #pragma unroll
    for (int j = 0; j < 8; ++j)
        tmp.s[j] = f2bf(W[(size_t)(kbase + j) * Dc + nc] * scale);
    *(uint4*)&Wf[(size_t)wi * 8] = tmp.v;
}

// ---------------------------------------------------------------------------
// QKV (unchanged): grid 1024, block 256 = 4 waves; 16 rows x 192 cols.
// ---------------------------------------------------------------------------
__global__ __launch_bounds__(256) void qkv_kernel(
    const float* __restrict__ x, const unsigned short* __restrict__ Wf,
    unsigned short* __restrict__ Qb, unsigned short* __restrict__ Kb,
    unsigned short* __restrict__ Vtb)
{
    __shared__ __align__(16) unsigned short Xs[2][16][72];  // 4.6 KB
    __shared__ __align__(16) unsigned short Ot[16][200];    // 6.4 KB bounce
    const int t = threadIdx.x;
    const int lane = t & 63, w = t >> 6;
    const int lm = lane & 15, quad = lane >> 4;
    const int row0 = blockIdx.x * 16;
    const int sr = t >> 4, sc4 = (t & 15) * 4;   // 16 rows x 16 float4-chunks

    float4 xv;
    auto load_x = [&](int k0) {
        xv = *(const float4*)&x[(size_t)(row0 + sr) * Fc + k0 + sc4];
    };
    load_x(0);

    float4v acc[3];
    #pragma unroll
    for (int n = 0; n < 3; ++n) acc[n] = float4v{0.f, 0.f, 0.f, 0.f};

    int buf = 0;
    #pragma unroll
    for (int k0 = 0; k0 < Fc; k0 += 64, buf ^= 1) {
        uint2 pk;
        pk.x = pk2(xv.x, xv.y); pk.y = pk2(xv.z, xv.w);
        *(uint2*)&Xs[buf][sr][sc4] = pk;
        __syncthreads();                          // one barrier per iter (dbuf)
        if (k0 + 64 < Fc) load_x(k0 + 64);

        short8 af[2];
        #pragma unroll
        for (int h = 0; h < 2; ++h)
            af[h] = *(const short8*)&Xs[buf][lm][h * 32 + quad * 8];

        #pragma unroll
        for (int n = 0; n < 3; ++n) {
            const int nt = 3 * w + n;
            #pragma unroll
            for (int h = 0; h < 2; ++h) {
                const int kchunk = (k0 >> 5) + h;
                short8 bf_ = *(const short8*)&Wf[(size_t)((nt * 16 + kchunk) * 64 + lane) * 8];
                acc[n] = __builtin_amdgcn_mfma_f32_16x16x32_bf16(af[h], bf_, acc[n], 0, 0, 0);
            }
        }
    }

    // ---- epilogue: C-frags -> LDS bounce, coalesced out ----
    __syncthreads();
    #pragma unroll
    for (int n = 0; n < 3; ++n)
        #pragma unroll
        for (int r = 0; r < 4; ++r)
            Ot[quad * 4 + r][(3 * w + n) * 16 + lm] = f2bf(acc[n][r]);
    __syncthreads();

    {
        const int r2 = t >> 4, c2 = (t & 15) * 4;     // 16 rows x 4-short chunks
        *(uint2*)&Qb[(size_t)(row0 + r2) * Dc + c2] = *(const uint2*)&Ot[r2][c2];
        *(uint2*)&Kb[(size_t)(row0 + r2) * Dc + c2] = *(const uint2*)&Ot[r2][64 + c2];
    }
    {
        const int d = t >> 2, s4 = (t & 3) * 4;       // V transpose: 64 d x 16 s
        union { uint2 v; unsigned short s[4]; } tmp;
        #pragma unroll
        for (int j = 0; j < 4; ++j) tmp.s[j] = Ot[s4 + j][128 + d];
        const int bb = row0 >> 12, s0r = row0 & (Sc - 1);
        *(uint2*)&Vtb[((size_t)bb * Dc + d) * Sc + s0r + s4] = tmp.v;
    }
}

// ---------------------------------------------------------------------------
// Attention R7: R6 main loop UNCHANGED (128 q/block, SPLIT=8, counted-vmcnt
// double-barrier, in-reg P, setprio). Combine FUSED via split-K semaphore:
// after writing its Op/lp partial, each block does __syncthreads (drains
// stores) -> t0: __threadfence (device release, wbL2) + atomicAdd(sem) ->
// the 8th arriver re-reads all 8 partials (never locally cached; writers
// flushed) and writes final out in the SAME z-order as the old combine
// kernel -> bit-identical result. The 4th kernel launch is eliminated.
// ---------------------------------------------------------------------------
__global__ __launch_bounds__(256) void attn_kernel(
    const unsigned short* __restrict__ Qb, const unsigned short* __restrict__ Kb,
    const unsigned short* __restrict__ Vtb,
    float* __restrict__ Op, float* __restrict__ lp,
    unsigned* __restrict__ sem, float* __restrict__ out)
{
    __shared__ __align__(16) char smem[36864];   // 2x16KB K/V dbuf + overlay room
    __shared__ int lastFlag;

    const int t = threadIdx.x;
    const int lane = t & 63, w = t >> 6;
    const int l31 = lane & 31, lh = lane >> 5;
    const int b = blockIdx.y, z = blockIdx.z;
    const int q0 = blockIdx.x * 128 + w * 32;
    const size_t qkbase = (size_t)b * Sc * Dc;
    const size_t vbase  = (size_t)b * Dc * Sc;
    const int k0base = z * (Sc / SPLIT);

    // Q B-frags: B[k=d][n=qrow]
    short8 qf[4];
    #pragma unroll
    for (int c = 0; c < 4; ++c)
        qf[c] = *(const short8*)&Qb[qkbase + (size_t)(q0 + l31) * Dc + c * 16 + lh * 8];

    float16v O0, O1;
    #pragma unroll
    for (int r = 0; r < 16; ++r) { O0[r] = 0.f; O1[r] = 0.f; }
    float lA = 0.f, lB = 0.f;

    // ---- gload_lds staging (unchanged from R6) ----
    const int rowInW = lane >> 3;                     // 0..7
    const int srcChunk = (lane & 7) ^ rowInW;         // XOR pre-swizzle
    auto stage = [&](int p, int k0) {
        char* base = smem + p * 16384;
        #pragma unroll
        for (int j = 0; j < 2; ++j) {
            const int row = w * 16 + j * 8 + rowInW;
            const unsigned short* gk = Kb + qkbase + (size_t)(k0 + row) * Dc + srcChunk * 8;
            const unsigned short* gv = Vtb + vbase + (size_t)row * Sc + k0 + srcChunk * 8;
            __builtin_amdgcn_global_load_lds(
                (const __attribute__((address_space(1))) void*)gk,
                (__attribute__((address_space(3))) void*)(base + (w * 16 + j * 8) * 128),
                16, 0, 0);
            __builtin_amdgcn_global_load_lds(
                (const __attribute__((address_space(1))) void*)gv,
                (__attribute__((address_space(3))) void*)(base + 8192 + (w * 16 + j * 8) * 128),
                16, 0, 0);
        }
    };

    const int rx = l31 & 7;
    auto rd = [&](const char* buf, int row, int cc) -> short8 {
        return *(const short8*)(buf + row * 128 + ((cc ^ rx) * 16));
    };

    auto mk_pb = [&](const float16v& s, int g) -> short8 {
        unsigned X0 = cvtpk2(s[8 * g + 0], s[8 * g + 1]);
        unsigned X1 = cvtpk2(s[8 * g + 2], s[8 * g + 3]);
        unsigned Y0 = cvtpk2(s[8 * g + 4], s[8 * g + 5]);
        unsigned Y1 = cvtpk2(s[8 * g + 6], s[8 * g + 7]);
        swap32(X0, Y0);
        swap32(X1, Y1);
        union { unsigned u[4]; short8 s8; } r;
        r.u[0] = X0; r.u[1] = X1; r.u[2] = Y0; r.u[3] = Y1;
        return r.s8;
    };

    stage(0, k0base);                 // tile 0 -> buf 0
    stage(1, k0base + KT);            // tile 1 -> buf 1 (8 loads in flight)

    int p = 0;
    for (int kt = 0; kt < TILES; ++kt, p ^= 1) {
        if (kt + 1 < TILES) { asm volatile("s_waitcnt vmcnt(4)" ::: "memory"); }
        else                { asm volatile("s_waitcnt vmcnt(0)" ::: "memory"); }
        __builtin_amdgcn_sched_barrier(0);
        __builtin_amdgcn_s_barrier();          // all waves' tile-kt loads landed
        __builtin_amdgcn_sched_barrier(0);

        const char* kb = smem + p * 16384;
        const char* vb = kb + 8192;

        // ---- S^T = K.Q^T (scores in log2 domain) ----
        float16v s0, s1;
        #pragma unroll
        for (int r = 0; r < 16; ++r) { s0[r] = 0.f; s1[r] = 0.f; }
        __builtin_amdgcn_s_setprio(1);
        #pragma unroll
        for (int c = 0; c < 4; ++c) {
            short8 a0 = rd(kb, l31,      2 * c + lh);
            short8 a1 = rd(kb, 32 + l31, 2 * c + lh);
            s0 = __builtin_amdgcn_mfma_f32_32x32x16_bf16(a0, qf[c], s0, 0, 0, 0);
            s1 = __builtin_amdgcn_mfma_f32_32x32x16_bf16(a1, qf[c], s1, 0, 0, 0);
        }
        __builtin_amdgcn_s_setprio(0);

        // ---- p = exp2(s), accumulate l per-lane ----
        #pragma unroll
        for (int r = 0; r < 16; ++r) {
            float p0 = exp2fast(s0[r]); s0[r] = p0; lA += p0;
            float p1 = exp2fast(s1[r]); s1[r] = p1; lB += p1;
        }

        // ---- P^T in-register (T12) ----
        short8 pb0 = mk_pb(s0, 0);
        short8 pb1 = mk_pb(s0, 1);
        short8 pb2 = mk_pb(s1, 0);
        short8 pb3 = mk_pb(s1, 1);

        // ---- O^T += V^T.P^T ----
        __builtin_amdgcn_s_setprio(1);
        #pragma unroll
        for (int c = 0; c < 4; ++c) {
            short8 pb  = (c == 0) ? pb0 : (c == 1) ? pb1 : (c == 2) ? pb2 : pb3;
            short8 va0 = rd(vb, l31,      2 * c + lh);
            short8 va1 = rd(vb, 32 + l31, 2 * c + lh);
            O0 = __builtin_amdgcn_mfma_f32_32x32x16_bf16(va0, pb, O0, 0, 0, 0);
            O1 = __builtin_amdgcn_mfma_f32_32x32x16_bf16(va1, pb, O1, 0, 0, 0);
        }
        __builtin_amdgcn_s_setprio(0);

        asm volatile("s_waitcnt lgkmcnt(0)" ::: "memory");
        __builtin_amdgcn_sched_barrier(0);
        __builtin_amdgcn_s_barrier();          // all waves done READING buf p
        if (kt + 2 < TILES) stage(p, k0base + (kt + 2) * KT);   // refill buf p
    }

    // fold the lane^32 key-half partial into one l per q-row
    float l_i = lA + lB;
    l_i += __shfl_xor(l_i, 32);

    // ---- partial epilogue: overlay bounce on the (dead) arena ----
    __syncthreads();                                   // arena reads all done
    float* Of = (float*)(smem + w * 8704);             // 32 x 68 fp32 per wave
    #pragma unroll
    for (int r = 0; r < 16; ++r) {
        int d0 = (r & 3) + 8 * (r >> 2) + 4 * lh;
        Of[l31 * 68 + d0]      = O0[r];
        Of[l31 * 68 + 32 + d0] = O1[r];
    }
    const size_t obase = ((size_t)(z * Bc + b) * Sc + q0) * Dc;
    const int qr = lane >> 4, c4 = (lane & 15) * 4;
    #pragma unroll
    for (int i = 0; i < 8; ++i) {
        int q = i * 4 + qr;
        *(float4*)&Op[obase + (size_t)q * Dc + c4] = *(const float4*)&Of[q * 68 + c4];
    }
    if (lane < 32)
        lp[(z * Bc + b) * Sc + q0 + l31] = l_i;

    // ---- fused combine: device-scope release, count arrivals, last reduces ----
    __syncthreads();                 // all waves' Op/lp stores complete (vmcnt 0)
    if (t == 0) {
        __threadfence();                                   // release: flush L2
        unsigned old = atomicAdd(&sem[blockIdx.x * Bc + b], 1u);
        lastFlag = (old == SPLIT - 1);
        __threadfence();                                   // acquire: inv caches
    }
    __syncthreads();
    if (lastFlag) {
        const int BS = Bc * Sc;
        const int q0b = blockIdx.x * 128;
        const size_t stride = (size_t)BS * Dc;
        #pragma unroll
        for (int i = 0; i < 8; ++i) {
            int unit = i * 256 + t;              // 0..2047: 128 q x 16 float4s
            int q = unit >> 4, dc = (unit & 15) * 4;
            int bq = b * Sc + q0b + q;
            float L = 0.f;
            #pragma unroll
            for (int zz = 0; zz < SPLIT; ++zz) L += lp[zz * BS + bq];
            float inv = 1.f / L;
            size_t o = (size_t)bq * Dc + dc;
            float4 r = {0.f, 0.f, 0.f, 0.f};
            #pragma unroll
            for (int zz = 0; zz < SPLIT; ++zz) {
                float4 pz = *(const float4*)&Op[o + zz * stride];
                r.x += pz.x; r.y += pz.y; r.z += pz.z; r.w += pz.w;
            }
            r.x *= inv; r.y *= inv; r.z *= inv; r.w *= inv;
            *(float4*)&out[o] = r;
        }
    }
}

// ---------------------------------------------------------------------------
extern "C" void kernel_launch(void* const* d_in, const int* in_sizes, int n_in,
                              void* d_out, int out_size, void* d_ws, size_t ws_size,
                              hipStream_t stream) {
    const float* x  = (const float*)d_in[0];
    const float* Wq = (const float*)d_in[1];
    const float* Wk = (const float*)d_in[2];
    const float* Wv = (const float*)d_in[3];
    float* out = (float*)d_out;

    // ws layout (~40 MB)
    char* p = (char*)d_ws;
    unsigned short* Wf  = (unsigned short*)p;  p += (size_t)192 * Fc * 2;        // 196 KB
    unsigned short* Qb  = (unsigned short*)p;  p += (size_t)Bc * Sc * Dc * 2;    // 2 MB
    unsigned short* Kb  = (unsigned short*)p;  p += (size_t)Bc * Sc * Dc * 2;    // 2 MB
    unsigned short* Vtb = (unsigned short*)p;  p += (size_t)Bc * Sc * Dc * 2;    // 2 MB
    float* lp = (float*)p;                     p += (size_t)SPLIT * Bc * Sc * 4; // 512 KB
    unsigned* sem = (unsigned*)p;              p += 4096;                        // 128 ctr
    float* Op = (float*)p;                                                       // 33.5 MB

    prep_kernel<<<48, 256, 0, stream>>>(Wq, Wk, Wv, Wf, sem);
    qkv_kernel<<<Bc * Sc / 16, 256, 0, stream>>>(x, Wf, Qb, Kb, Vtb);
    attn_kernel<<<dim3(Sc / 128, Bc, SPLIT), 256, 0, stream>>>(Qb, Kb, Vtb, Op, lp, sem, out);
}

// Round 8
// 118.154 us; speedup vs baseline: 1.5378x; 1.5378x over previous
//
#include <hip/hip_runtime.h>

// Problem constants: x [B,S,F], Wq/Wk/Wv [F,D], out [B,S,D]
constexpr int Bc = 4, Sc = 4096, Fc = 512, Dc = 64;
constexpr int KT = 32;                 // keys per tile per wave
constexpr int NT = (Sc / 4) / KT;      // 32 tiles per wave (4 waves split the keys)

typedef __attribute__((ext_vector_type(8)))  short  short8;   // 8 bf16
typedef __attribute__((ext_vector_type(4)))  float  float4v;
typedef __attribute__((ext_vector_type(16))) float  float16v;
typedef __attribute__((ext_vector_type(2)))  unsigned int uint2v;

__device__ inline unsigned short f2bf(float f) {
    union { float f; unsigned u; } v; v.f = f;
    unsigned r = v.u + 0x7FFF + ((v.u >> 16) & 1);   // RTNE
    return (unsigned short)(r >> 16);
}
__device__ inline unsigned pk2(float a, float b) {   // pack 2 floats -> 2 bf16 (RTNE)
    union { float f; unsigned u; } x, y; x.f = a; y.f = b;
    unsigned ra = x.u + 0x7FFF + ((x.u >> 16) & 1);
    unsigned rb = y.u + 0x7FFF + ((y.u >> 16) & 1);
    return (ra >> 16) | (rb & 0xFFFF0000u);
}
// T12: single-instruction pack of 2 f32 -> 2 bf16 (RTNE, same as pk2).
__device__ inline unsigned cvtpk2(float lo, float hi) {
    unsigned r;
    asm("v_cvt_pk_bf16_f32 %0, %1, %2" : "=v"(r) : "v"(lo), "v"(hi));
    return r;
}
// native v_exp_f32 (2^x)
__device__ inline float exp2fast(float x) {
#if defined(__has_builtin) && __has_builtin(__builtin_amdgcn_exp2f)
    return __builtin_amdgcn_exp2f(x);
#else
    return __expf(x * 0.69314718055994531f);
#endif
}

// swap the 32-lane halves of two registers: a' = {a.lo | b.lo}, b' = {a.hi | b.hi}
__device__ inline void swap32(unsigned& a, unsigned& b) {
#if defined(__has_builtin) && __has_builtin(__builtin_amdgcn_permlane32_swap)
    uint2v r = __builtin_amdgcn_permlane32_swap(a, b, false, false);
    a = r[0]; b = r[1];
#else
    unsigned ax = (unsigned)__shfl_xor((int)a, 32);
    unsigned bx = (unsigned)__shfl_xor((int)b, 32);
    int upper = (threadIdx.x & 32) != 0;
    unsigned na = upper ? bx : a;
    unsigned nb = upper ? b  : ax;
    a = na; b = nb;
#endif
}

// ---------------------------------------------------------------------------
// Prep: Wf in MFMA-FRAGMENT ORDER. Entry (nt, kc, lane) holds 8 bf16:
//   Wf[((nt*16+kc)*64+lane)*8 + j] = Wt[nt*16 + (lane&15)][kc*32 + (lane>>4)*8 + j]
// Wt row n: 0-63 = Wq col n (x 0.125*log2e -> scores in log2 domain),
// 64-127 = Wk, 128-191 = Wv.
// ---------------------------------------------------------------------------
__global__ __launch_bounds__(256) void prep_kernel(
    const float* __restrict__ Wq, const float* __restrict__ Wk,
    const float* __restrict__ Wv, unsigned short* __restrict__ Wf)
{
    int wi = blockIdx.x * 256 + threadIdx.x;     // 12288 threads (48 blocks)
    int lane = wi & 63;
    int kc = (wi >> 6) & 15;
    int nt = wi >> 10;                           // 0..11
    int lm = lane & 15, quad = lane >> 4;
    int n = nt * 16 + lm;                        // 0..191
    const float* W = (n < 64) ? Wq : (n < 128) ? Wk : Wv;
    int nc = n & 63;
    float scale = (n < 64) ? 0.18033688011112042f : 1.0f;  // 0.125*log2(e)
    int kbase = kc * 32 + quad * 8;
    union { uint4 v; unsigned short s[8]; } tmp;
    #pragma unroll
    for (int j = 0; j < 8; ++j)
        tmp.s[j] = f2bf(W[(size_t)(kbase + j) * Dc + nc] * scale);
    *(uint4*)&Wf[(size_t)wi * 8] = tmp.v;
}

// ---------------------------------------------------------------------------
// QKV: grid 1024 (16 rows/block), block 256 = 4 waves. Block = 16 rows x 192
// cols (Q|K|V). Double-buffered Xs, one barrier/iter. B-frags = single
// coalesced short8 loads from fragment-ordered Wf (L2-hot, 196 KB).
// ---------------------------------------------------------------------------
__global__ __launch_bounds__(256) void qkv_kernel(
    const float* __restrict__ x, const unsigned short* __restrict__ Wf,
    unsigned short* __restrict__ Qb, unsigned short* __restrict__ Kb,
    unsigned short* __restrict__ Vtb)
{
    __shared__ __align__(16) unsigned short Xs[2][16][72];  // 4.6 KB
    __shared__ __align__(16) unsigned short Ot[16][200];    // 6.4 KB bounce
    const int t = threadIdx.x;
    const int lane = t & 63, w = t >> 6;
    const int lm = lane & 15, quad = lane >> 4;
    const int row0 = blockIdx.x * 16;
    const int sr = t >> 4, sc4 = (t & 15) * 4;   // 16 rows x 16 float4-chunks

    float4 xv;
    auto load_x = [&](int k0) {
        xv = *(const float4*)&x[(size_t)(row0 + sr) * Fc + k0 + sc4];
    };
    load_x(0);

    float4v acc[3];
    #pragma unroll
    for (int n = 0; n < 3; ++n) acc[n] = float4v{0.f, 0.f, 0.f, 0.f};

    int buf = 0;
    #pragma unroll
    for (int k0 = 0; k0 < Fc; k0 += 64, buf ^= 1) {
        uint2 pk;
        pk.x = pk2(xv.x, xv.y); pk.y = pk2(xv.z, xv.w);
        *(uint2*)&Xs[buf][sr][sc4] = pk;
        __syncthreads();                          // one barrier per iter (dbuf)
        if (k0 + 64 < Fc) load_x(k0 + 64);

        short8 af[2];
        #pragma unroll
        for (int h = 0; h < 2; ++h)
            af[h] = *(const short8*)&Xs[buf][lm][h * 32 + quad * 8];

        #pragma unroll
        for (int n = 0; n < 3; ++n) {
            const int nt = 3 * w + n;
            #pragma unroll
            for (int h = 0; h < 2; ++h) {
                const int kchunk = (k0 >> 5) + h;
                short8 bf_ = *(const short8*)&Wf[(size_t)((nt * 16 + kchunk) * 64 + lane) * 8];
                acc[n] = __builtin_amdgcn_mfma_f32_16x16x32_bf16(af[h], bf_, acc[n], 0, 0, 0);
            }
        }
    }

    // ---- epilogue: C-frags -> LDS bounce, coalesced out ----
    __syncthreads();
    #pragma unroll
    for (int n = 0; n < 3; ++n)
        #pragma unroll
        for (int r = 0; r < 4; ++r)
            Ot[quad * 4 + r][(3 * w + n) * 16 + lm] = f2bf(acc[n][r]);
    __syncthreads();

    {
        const int r2 = t >> 4, c2 = (t & 15) * 4;     // 16 rows x 4-short chunks
        *(uint2*)&Qb[(size_t)(row0 + r2) * Dc + c2] = *(const uint2*)&Ot[r2][c2];
        *(uint2*)&Kb[(size_t)(row0 + r2) * Dc + c2] = *(const uint2*)&Ot[r2][64 + c2];
    }
    {
        const int d = t >> 2, s4 = (t & 3) * 4;       // V transpose: 64 d x 16 s
        union { uint2 v; unsigned short s[4]; } tmp;
        #pragma unroll
        for (int j = 0; j < 4; ++j) tmp.s[j] = Ot[s4 + j][128 + d];
        const int bb = row0 >> 12, s0r = row0 & (Sc - 1);
        *(uint2*)&Vtb[((size_t)bb * Dc + d) * Sc + s0r + s4] = tmp.v;
    }
}

// ---------------------------------------------------------------------------
// Attention (R4 structure, empirical best of the session): NO split-K across
// blocks. Block = 32 q-rows x ALL 4096 keys; the 4 waves each own a
// contiguous 1024-key quarter with a PRIVATE 16KB LDS slice (dbuf 4KB K +
// 4KB V per 32-key tile). Zero barriers in the main loop: per-wave counted
// vmcnt(8) pipeline (T3/T4), setprio around MFMA (T5), in-register P (T12).
// One __syncthreads at the end; 4 partial O/l reduced in LDS; block writes
// FINAL out (no Op/lp partials, no combine kernel). Grid 512 = 2 blocks/CU.
// XCD-chunked block swizzle (T1).
// Session notes: this ~37us attn + 3-launch pipeline beat the faster 30.5us
// shared-tile attn + combine-kernel variants on total time (118.8 vs 120-121);
// per-block device-scope fence fusion (R7) regressed 3x — do not revisit.
// ---------------------------------------------------------------------------
__global__ __launch_bounds__(256) void attn_kernel(
    const unsigned short* __restrict__ Qb, const unsigned short* __restrict__ Kb,
    const unsigned short* __restrict__ Vtb,
    float* __restrict__ out)
{
    __shared__ __align__(16) char smem[65536];   // 4 waves x 16KB private slices

    const int t = threadIdx.x;
    const int lane = t & 63, w = t >> 6;
    const int l31 = lane & 31, lh = lane >> 5;

    // XCD swizzle: 512 wgs, 8 XCDs -> 64-contiguous chunks (bijective, 512%8==0)
    const int orig = blockIdx.x;
    const int swz = (orig & 7) * 64 + (orig >> 3);
    const int b = swz >> 7;                      // 0..3
    const int q0 = (swz & 127) * 32;             // 0..4064
    const size_t qkbase = (size_t)b * Sc * Dc;
    const size_t vbase  = (size_t)b * Dc * Sc;
    const int kw0 = w * (Sc / 4);                // this wave's key-range start

    // Q B-frags: B[k=d][n=qrow]; all 4 waves use the same 32 q-rows
    short8 qf[4];
    #pragma unroll
    for (int c = 0; c < 4; ++c)
        qf[c] = *(const short8*)&Qb[qkbase + (size_t)(q0 + l31) * Dc + c * 16 + lh * 8];

    float16v O0, O1;
    #pragma unroll
    for (int r = 0; r < 16; ++r) { O0[r] = 0.f; O1[r] = 0.f; }
    float lA = 0.f, lB = 0.f;

    char* const slice = smem + w * 16384;        // wave-private
    // pre-swizzled global source chunks (rule 21: linear LDS dest, swz source)
    const int sk8 = (lane & 7) ^ ((lane >> 3) & 7);   // K: row&7 XOR, 8 slots/128B row
    const int sv4 = (lane & 3) ^ ((lane >> 3) & 3);   // V: (row>>1)&3 XOR, 4 slots/64B row

    auto stage = [&](int p, int k0) {
        char* kb = slice + p * 8192;
        char* vb = kb + 4096;
        #pragma unroll
        for (int j = 0; j < 4; ++j) {
            const int krow = j * 8 + (lane >> 3);          // K: 8 rows/load, 128B rows
            const unsigned short* gk = Kb + qkbase + (size_t)(k0 + krow) * Dc + sk8 * 8;
            __builtin_amdgcn_global_load_lds(
                (const __attribute__((address_space(1))) void*)gk,
                (__attribute__((address_space(3))) void*)(kb + j * 1024), 16, 0, 0);
            const int vrow = j * 16 + (lane >> 2);         // V: 16 rows/load, 64B rows
            const unsigned short* gv = Vtb + vbase + (size_t)vrow * Sc + k0 + sv4 * 8;
            __builtin_amdgcn_global_load_lds(
                (const __attribute__((address_space(1))) void*)gv,
                (__attribute__((address_space(3))) void*)(vb + j * 1024), 16, 0, 0);
        }
    };

    // swizzled reads (apply the same XOR the source placement used)
    auto rdK = [&](const char* kb, int row, int cc) -> short8 {
        return *(const short8*)(kb + row * 128 + ((cc ^ (row & 7)) * 16));
    };
    auto rdV = [&](const char* vb, int row, int cc) -> short8 {
        return *(const short8*)(vb + row * 64 + ((cc ^ ((row >> 1) & 3)) * 16));
    };

    // PV B-frag from 8 consecutive s-regs (group g): 4 cvt_pk + 2 permlane
    auto mk_pb = [&](const float16v& s, int g) -> short8 {
        unsigned X0 = cvtpk2(s[8 * g + 0], s[8 * g + 1]);
        unsigned X1 = cvtpk2(s[8 * g + 2], s[8 * g + 3]);
        unsigned Y0 = cvtpk2(s[8 * g + 4], s[8 * g + 5]);
        unsigned Y1 = cvtpk2(s[8 * g + 6], s[8 * g + 7]);
        swap32(X0, Y0);
        swap32(X1, Y1);
        union { unsigned u[4]; short8 s8; } r;
        r.u[0] = X0; r.u[1] = X1; r.u[2] = Y0; r.u[3] = Y1;
        return r.s8;
    };

    stage(0, kw0);

    int p = 0;
    for (int kt = 0; kt < NT; ++kt, p ^= 1) {
        if (kt + 1 < NT) {
            stage(p ^ 1, kw0 + (kt + 1) * KT);
            asm volatile("s_waitcnt vmcnt(8)" ::: "memory");   // tile kt's 8 loads done
        } else {
            asm volatile("s_waitcnt vmcnt(0)" ::: "memory");
        }
        __builtin_amdgcn_sched_barrier(0);
        const char* kb = slice + p * 8192;
        const char* vb = kb + 4096;

        // ---- S^T = K.Q^T (32 keys x 32 q, log2 domain) ----
        float16v s;
        #pragma unroll
        for (int r = 0; r < 16; ++r) s[r] = 0.f;
        __builtin_amdgcn_s_setprio(1);
        #pragma unroll
        for (int c = 0; c < 4; ++c) {
            short8 a = rdK(kb, l31, 2 * c + lh);
            s = __builtin_amdgcn_mfma_f32_32x32x16_bf16(a, qf[c], s, 0, 0, 0);
        }
        __builtin_amdgcn_s_setprio(0);

        // ---- p = exp2(s), accumulate l per-lane ----
        #pragma unroll
        for (int r = 0; r < 16; ++r) {
            float pe = exp2fast(s[r]); s[r] = pe;
            if (r < 8) lA += pe; else lB += pe;
        }

        // ---- P^T in-register (T12) ----
        short8 pb0 = mk_pb(s, 0);                 // keys 0-15
        short8 pb1 = mk_pb(s, 1);                 // keys 16-31

        // ---- O^T += V^T.P^T ----
        __builtin_amdgcn_s_setprio(1);
        #pragma unroll
        for (int c = 0; c < 2; ++c) {
            short8 pb  = c ? pb1 : pb0;
            short8 va0 = rdV(vb, l31,      2 * c + lh);
            short8 va1 = rdV(vb, 32 + l31, 2 * c + lh);
            O0 = __builtin_amdgcn_mfma_f32_32x32x16_bf16(va0, pb, O0, 0, 0, 0);
            O1 = __builtin_amdgcn_mfma_f32_32x32x16_bf16(va1, pb, O1, 0, 0, 0);
        }
        __builtin_amdgcn_s_setprio(0);
    }

    // per-wave l: fold lane^32 key-half
    float l_i = lA + lB;
    l_i += __shfl_xor(l_i, 32);

    // ---- per-wave partials -> OWN slice (no barrier needed: private) ----
    float* Of = (float*)slice;                    // 32 q x 68 fp32
    #pragma unroll
    for (int r = 0; r < 16; ++r) {
        int d0 = (r & 3) + 8 * (r >> 2) + 4 * lh;
        Of[l31 * 68 + d0]      = O0[r];
        Of[l31 * 68 + 32 + d0] = O1[r];
    }
    float* lw = (float*)(slice + 8704);
    if (lane < 32) lw[l31] = l_i;

    __syncthreads();

    // ---- cross-wave reduce + final write (thread t: q = t>>3, 8 d's) ----
    {
        const int q = t >> 3, d8 = (t & 7) * 8;
        float acc8[8];
        #pragma unroll
        for (int j = 0; j < 8; ++j) acc8[j] = 0.f;
        float L = 0.f;
        #pragma unroll
        for (int w2 = 0; w2 < 4; ++w2) {
            const float* OfW = (const float*)(smem + w2 * 16384);
            const float* lwW = (const float*)(smem + w2 * 16384 + 8704);
            L += lwW[q];
            #pragma unroll
            for (int j = 0; j < 8; ++j) acc8[j] += OfW[q * 68 + d8 + j];
        }
        float inv = 1.f / L;
        float4 o0, o1;
        o0.x = acc8[0] * inv; o0.y = acc8[1] * inv; o0.z = acc8[2] * inv; o0.w = acc8[3] * inv;
        o1.x = acc8[4] * inv; o1.y = acc8[5] * inv; o1.z = acc8[6] * inv; o1.w = acc8[7] * inv;
        float* op = out + ((size_t)b * Sc + q0 + q) * Dc + d8;
        *(float4*)op = o0;
        *(float4*)(op + 4) = o1;
    }
}

// ---------------------------------------------------------------------------
extern "C" void kernel_launch(void* const* d_in, const int* in_sizes, int n_in,
                              void* d_out, int out_size, void* d_ws, size_t ws_size,
                              hipStream_t stream) {
    const float* x  = (const float*)d_in[0];
    const float* Wq = (const float*)d_in[1];
    const float* Wk = (const float*)d_in[2];
    const float* Wv = (const float*)d_in[3];
    float* out = (float*)d_out;

    // ws layout (~6.2 MB)
    char* p = (char*)d_ws;
    unsigned short* Wf  = (unsigned short*)p;  p += (size_t)192 * Fc * 2;        // 196 KB
    unsigned short* Qb  = (unsigned short*)p;  p += (size_t)Bc * Sc * Dc * 2;    // 2 MB
    unsigned short* Kb  = (unsigned short*)p;  p += (size_t)Bc * Sc * Dc * 2;    // 2 MB
    unsigned short* Vtb = (unsigned short*)p;                                    // 2 MB

    prep_kernel<<<48, 256, 0, stream>>>(Wq, Wk, Wv, Wf);
    qkv_kernel<<<Bc * Sc / 16, 256, 0, stream>>>(x, Wf, Qb, Kb, Vtb);
    attn_kernel<<<dim3(Sc / 32 * Bc), 256, 0, stream>>>(Qb, Kb, Vtb, out);
}